// Round 4
// baseline (271.209 us; speedup 1.0000x reference)
//
#include <hip/hip_runtime.h>
#include <hip/hip_bf16.h>
#include <math.h>

// Problem constants
#define B    8
#define C4   64
#define CQ   16
#define NN   512
#define L4   12
#define NCH1 8            // n's per k1 block
#define KSPL 4            // K-split in pass-2 GEMM
#define KT   128          // k-tile in final kernel

// workspace layout (float offsets)
#define O_T    0                              // T[b][n][c][q] (m=c*16+q)   4194304
#define O_FL   (O_T + (size_t)B*NN*C4*CQ)     // Fl[b][q][k]                  65536
#define O_XX   (O_FL + (size_t)B*CQ*NN)       // [B][CQ]                        128
#define O_YY   (O_XX + B*CQ)                  //                                128
#define O_L2   (O_YY + B*CQ)                  // [B] 1/l2 (+pad)                 16
#define O_AMAX (O_L2 + 16)                    // A[b][n][k]                 2097152
#define O_WARR (O_AMAX + (size_t)B*NN*NN)     // W[b][n][k]=A[b][k][n]      2097152
#define O_PART (O_WARR + (size_t)B*NN*NN)     // [B][KSPL][C4][NN]          1048576

// bank-swizzled LDS indexers: +4-float skew every 32 columns
#define FLS_IDX(q, col)  ((q)*288 + (col) + ((((col)>>5))<<2))   // rows of 256 -> 288
#define WS_IDX(nl, col)  ((nl)*576 + (col) + ((((col)>>5))<<2))  // rows of 512 -> 576

// K1: Fc, Fl, norms, and T[n,c,q] = sum_j Fc[q,n,j]*x[c,n,j]
__global__ __launch_bounds__(256) void k1_fc(const float* __restrict__ x,
                                             const float* __restrict__ Wc,
                                             const float* __restrict__ bc,
                                             float* __restrict__ ws) {
  int blk = blockIdx.x;                // b*64 + nchunk
  int b = blk >> 6;
  int n0 = (blk & 63) * NCH1;
  int t = threadIdx.x;
  __shared__ __align__(16) float xs[C4*NCH1*L4];   // [c][nl][j] 6144
  __shared__ float wcs[CQ*C4];                     // [q][c]
  __shared__ float bcs[CQ];
  __shared__ __align__(16) float fcs[NCH1*CQ*L4];  // [nl][q][j] 1536

  for (int e = t; e < CQ*C4; e += 256) wcs[e] = Wc[e];
  if (t < CQ) bcs[t] = bc[t];
  const float* xb = x + (size_t)b*C4*NN*L4 + (size_t)n0*L4;
  for (int f = t; f < (C4*NCH1*L4)/4; f += 256) {
    int c = f / (NCH1*L4/4);
    int r = f - c*(NCH1*L4/4);
    float4 v = *(const float4*)(xb + (size_t)c*NN*L4 + r*4);
    *(float4*)(xs + c*(NCH1*L4) + r*4) = v;
  }
  __syncthreads();
  for (int e = t; e < NCH1*CQ*L4; e += 256) {
    int nl = e / (CQ*L4);
    int rem = e - nl*(CQ*L4);
    int q = rem / L4, j = rem - q*L4;
    float acc = bcs[q];
    #pragma unroll
    for (int c = 0; c < C4; ++c) acc += wcs[q*C4 + c] * xs[c*(NCH1*L4) + nl*L4 + j];
    fcs[e] = acc;
    if (j == L4-1) ws[O_FL + ((size_t)b*CQ + q)*NN + n0 + nl] = acc;
  }
  __syncthreads();
  if (t < CQ) {
    float yy = 0.f, xx = 0.f;
    for (int nl = 0; nl < NCH1; ++nl) {
      #pragma unroll
      for (int j = 0; j < L4; ++j) { float v = fcs[nl*(CQ*L4) + t*L4 + j]; yy += v*v; }
      float w = fcs[nl*(CQ*L4) + t*L4 + (L4-1)];
      xx += w*w;
    }
    atomicAdd(ws + O_YY + b*CQ + t, yy);
    atomicAdd(ws + O_XX + b*CQ + t, xx);
  }
  {
    int c = t >> 2, q0 = (t & 3) * 4;
    for (int nl = 0; nl < NCH1; ++nl) {
      float xr[L4];
      *(float4*)&xr[0] = *(const float4*)(xs + c*(NCH1*L4) + nl*L4);
      *(float4*)&xr[4] = *(const float4*)(xs + c*(NCH1*L4) + nl*L4 + 4);
      *(float4*)&xr[8] = *(const float4*)(xs + c*(NCH1*L4) + nl*L4 + 8);
      float4 tv; float* tvp = (float*)&tv;
      #pragma unroll
      for (int i = 0; i < 4; ++i) {
        float a = 0.f;
        #pragma unroll
        for (int j = 0; j < L4; ++j) a += fcs[nl*(CQ*L4) + (q0+i)*L4 + j] * xr[j];
        tvp[i] = a;
      }
      *(float4*)(ws + O_T + ((size_t)b*NN + n0 + nl)*(C4*CQ) + t*4) = tv;
    }
  }
}

// K1b: l2inv[b]
__global__ void k1b_l2(float* __restrict__ ws) {
  int t = threadIdx.x;              // 128 threads = B*CQ
  __shared__ float s[B*CQ];
  s[t] = sqrtf(ws[O_XX + t]) * sqrtf(ws[O_YY + t]);
  __syncthreads();
  if (t < B) {
    float sum = 0.f;
    #pragma unroll
    for (int q = 0; q < CQ; ++q) sum += s[t*CQ + q];
    ws[O_L2 + t] = 1.0f / sum;
  }
}

// K2 (pass 1): per (n, khalf): R[c 64][k 256] = Tt^T(16x64) * Fl(16x256),
// A[n][k] = relu(tanh(l2inv * max_c R)). 256 thr = 8 cg x 32 kg, frag 8c x 8k.
__global__ __launch_bounds__(256, 4) void k2_amax(float* __restrict__ ws) {
  int blk = blockIdx.x;             // (b*512+n)*2 + khalf
  int khalf = blk & 1;
  int bn = blk >> 1;
  int b = bn >> 9;
  int t = threadIdx.x;
  int cg = t >> 5;                  // 0..7
  int kg = t & 31;                  // 0..31
  __shared__ __align__(16) float Tt[16*64];     // [q][c]
  __shared__ __align__(16) float Fls[16*288];   // swizzled [q][256]
  __shared__ __align__(16) float red[8*264];    // [cg][256+pad]
  // stage Tt: T[n] is 1024 floats [c][q]; transpose to [q][c]
  {
    float4 v = *(const float4*)(ws + O_T + (size_t)bn*1024 + t*4);
    int c = t >> 2, q0 = (t & 3) * 4;
    Tt[ q0     *64 + c] = v.x;
    Tt[(q0+1)*64 + c] = v.y;
    Tt[(q0+2)*64 + c] = v.z;
    Tt[(q0+3)*64 + c] = v.w;
  }
  // stage Fl tile [16][256] (swizzled)
  const float* flb = ws + O_FL + (size_t)b*CQ*NN + khalf*256;
  #pragma unroll
  for (int i = 0; i < 4; ++i) {
    int f = t + 256*i;              // 0..1023 float4s
    int q = f >> 6, col = (f & 63) * 4;
    float4 v = *(const float4*)(flb + (size_t)q*NN + col);
    *(float4*)&Fls[FLS_IDX(q, col)] = v;
  }
  float l2inv = ws[O_L2 + b];
  __syncthreads();
  float acc[8][8];
  #pragma unroll
  for (int i = 0; i < 8; ++i)
    #pragma unroll
    for (int j = 0; j < 8; ++j) acc[i][j] = 0.f;
  #pragma unroll
  for (int q = 0; q < 16; ++q) {
    float a[8], bb[8];
    *(float4*)&a[0] = *(const float4*)&Tt[q*64 + cg*8];       // broadcast (2 addrs/wave)
    *(float4*)&a[4] = *(const float4*)&Tt[q*64 + cg*8 + 4];
    *(float4*)&bb[0] = *(const float4*)&Fls[FLS_IDX(q, kg*8)];
    *(float4*)&bb[4] = *(const float4*)&Fls[FLS_IDX(q, kg*8) + 4];
    #pragma unroll
    for (int i = 0; i < 8; ++i)
      #pragma unroll
      for (int j = 0; j < 8; ++j) acc[i][j] += a[i]*bb[j];
  }
  // max over this thread's 8 c's
  float m[8];
  #pragma unroll
  for (int j = 0; j < 8; ++j) {
    float mm = acc[0][j];
    #pragma unroll
    for (int i = 1; i < 8; ++i) mm = fmaxf(mm, acc[i][j]);
    m[j] = mm;
  }
  *(float4*)&red[cg*264 + kg*8]     = *(float4*)&m[0];
  *(float4*)&red[cg*264 + kg*8 + 4] = *(float4*)&m[4];
  __syncthreads();
  // final: thread t owns k_loc = t
  float mm = red[t];
  #pragma unroll
  for (int g = 1; g < 8; ++g) mm = fmaxf(mm, red[g*264 + t]);
  float aout = fmaxf(tanhf(mm*l2inv), 0.f);
  ws[O_AMAX + (size_t)bn*NN + khalf*256 + t] = aout;
}

// K2b: W[b][n][k] = A[b][k][n]
__global__ __launch_bounds__(256) void k2b_tr(float* __restrict__ ws) {
  int blk = blockIdx.x;             // b*256 + bi*16 + bj
  int b  = blk >> 8;
  int bi = (blk >> 4) & 15;
  int bj = blk & 15;
  int t = threadIdx.x;
  int tx = t & 31, ty = t >> 5;
  __shared__ float tile[32][33];
  const float* am = ws + O_AMAX + (size_t)b*NN*NN;
  float* wa = ws + O_WARR + (size_t)b*NN*NN;
  #pragma unroll
  for (int i = 0; i < 4; ++i) {
    int row = ty + i*8;
    tile[row][tx] = am[(size_t)(bi*32+row)*NN + bj*32 + tx];
  }
  __syncthreads();
  #pragma unroll
  for (int i = 0; i < 4; ++i) {
    int row = ty + i*8;
    wa[(size_t)(bj*32+row)*NN + bi*32 + tx] = tile[tx][row];
  }
}

// K3 (pass 2): U[m,k] = sum_n T[n,m]*W[n,k]; epilogue q-reduce with Fl*l2inv.
// Grid: (b*KSPL+ks)*32 + mb. Block: m-range 32 (wave w owns m_local w*8..+8,
// A-operand wave-uniform -> LDS broadcast), k = lane*8..+8 (full 512).
__global__ __launch_bounds__(256, 4) void k3_gemm(float* __restrict__ ws) {
  int id = blockIdx.x;
  int mb = id & 31;
  int ks = (id >> 5) & 3;
  int b  = id >> 7;
  int t = threadIdx.x;
  int w = t >> 6;                   // wave 0..3
  int lane = t & 63;
  __shared__ __align__(16) float Ws_[8*576];   // swizzled [nl][512]
  __shared__ __align__(16) float Ts[8*32];     // [nl][m_local 32]
  __shared__ __align__(16) float red[2*512];
  float acc[8][8];
  #pragma unroll
  for (int i = 0; i < 8; ++i)
    #pragma unroll
    for (int j = 0; j < 8; ++j) acc[i][j] = 0.f;
  const float* Wb = ws + O_WARR + (size_t)b*NN*NN;   // [n][k]
  const float* Tb = ws + O_T + (size_t)b*NN*1024;    // [n][m]

  for (int ch = 0; ch < 16; ++ch) {
    int n0 = ks*128 + ch*8;
    __syncthreads();
    // stage W rows n0..n0+8 (4096 consecutive floats), swizzled
    #pragma unroll
    for (int i = 0; i < 4; ++i) {
      int f = t + 256*i;            // float4 index 0..1023
      int nl = f >> 7, col = (f & 127) * 4;
      float4 v = *(const float4*)(Wb + (size_t)n0*NN + f*4);
      *(float4*)&Ws_[WS_IDX(nl, col)] = v;
    }
    if (t < 64) {
      int nl = t >> 3, fq = t & 7;
      *(float4*)&Ts[nl*32 + fq*4] =
        *(const float4*)(Tb + (size_t)(n0+nl)*1024 + mb*32 + fq*4);
    }
    __syncthreads();
    #pragma unroll
    for (int nl = 0; nl < 8; ++nl) {
      float a[8], bb[8];
      *(float4*)&a[0] = *(const float4*)&Ts[nl*32 + w*8];      // 1 addr/wave: broadcast
      *(float4*)&a[4] = *(const float4*)&Ts[nl*32 + w*8 + 4];
      *(float4*)&bb[0] = *(const float4*)&Ws_[WS_IDX(nl, lane*8)];
      *(float4*)&bb[4] = *(const float4*)&Ws_[WS_IDX(nl, lane*8) + 4];
      #pragma unroll
      for (int i = 0; i < 8; ++i)
        #pragma unroll
        for (int j = 0; j < 8; ++j) acc[i][j] += a[i]*bb[j];
    }
  }
  // epilogue: m = mb*32 + w*8 + i = c*16+q -> c = mb*2 + (w>>1), q = (w&1)*8+i
  float l2inv = ws[O_L2 + b];
  int qh = w & 1;
  int cl = w >> 1;
  const float* flb = ws + O_FL + (size_t)b*CQ*NN;
  float s[8];
  #pragma unroll
  for (int j = 0; j < 8; ++j) s[j] = 0.f;
  #pragma unroll
  for (int i = 0; i < 8; ++i) {
    int q = qh*8 + i;
    float f[8];
    *(float4*)&f[0] = *(const float4*)(flb + (size_t)q*NN + lane*8);
    *(float4*)&f[4] = *(const float4*)(flb + (size_t)q*NN + lane*8 + 4);
    #pragma unroll
    for (int j = 0; j < 8; ++j) s[j] += f[j]*acc[i][j];
  }
  #pragma unroll
  for (int j = 0; j < 8; ++j) s[j] *= l2inv;
  __syncthreads();
  if (qh == 1) {
    *(float4*)&red[cl*512 + lane*8]     = *(float4*)&s[0];
    *(float4*)&red[cl*512 + lane*8 + 4] = *(float4*)&s[4];
  }
  __syncthreads();
  if (qh == 0) {
    float4 p0 = *(const float4*)&red[cl*512 + lane*8];
    float4 p1 = *(const float4*)&red[cl*512 + lane*8 + 4];
    s[0]+=p0.x; s[1]+=p0.y; s[2]+=p0.z; s[3]+=p0.w;
    s[4]+=p1.x; s[5]+=p1.y; s[6]+=p1.z; s[7]+=p1.w;
    int c = mb*2 + cl;
    float* outp = ws + O_PART + (((size_t)(b*KSPL + ks)*C4 + c)*NN);
    *(float4*)(outp + lane*8)     = *(float4*)&s[0];
    *(float4*)(outp + lane*8 + 4) = *(float4*)&s[4];
  }
}

// K4: reduce KSPL partials -> xg, then Fg = W_gcn xg + b_gcn
__global__ __launch_bounds__(256) void k4_out(const float* __restrict__ Wg,
                                              const float* __restrict__ bg,
                                              const float* __restrict__ ws,
                                              float* __restrict__ out) {
  int blk = blockIdx.x;             // b*4 + kc
  int b = blk >> 2, kc = blk & 3;
  int t = threadIdx.x;
  __shared__ float xg[C4][KT+1];
  __shared__ float wg[C4*C4];
  for (int e = t; e < C4*C4; e += 256) wg[e] = Wg[e];
  for (int e = t; e < C4*KT; e += 256) {
    int c = e >> 7, kk = e & (KT-1);
    float s = 0.f;
    #pragma unroll
    for (int chn = 0; chn < KSPL; ++chn)
      s += ws[O_PART + (((size_t)(b*KSPL + chn)*C4 + c)*NN) + kc*KT + kk];
    xg[c][kk] = s;
  }
  __syncthreads();
  int kk = t & (KT-1);
  int ohalf = t >> 7;
  for (int oi = 0; oi < 32; ++oi) {
    int o = ohalf*32 + oi;
    float acc = bg[o];
    #pragma unroll
    for (int c = 0; c < C4; ++c) acc += wg[o*C4 + c] * xg[c][kk];
    out[((size_t)(b*C4 + o))*NN + kc*KT + kk] = acc;
  }
}

extern "C" void kernel_launch(void* const* d_in, const int* in_sizes, int n_in,
                              void* d_out, int out_size, void* d_ws, size_t ws_size,
                              hipStream_t stream) {
  const float* x  = (const float*)d_in[0];
  const float* Wc = (const float*)d_in[1];
  const float* bc = (const float*)d_in[2];
  const float* Wg = (const float*)d_in[3];
  const float* bg = (const float*)d_in[4];
  float* ws  = (float*)d_ws;
  float* out = (float*)d_out;

  hipMemsetAsync(ws + O_XX, 0, (2*B*CQ + 16)*sizeof(float), stream);

  k1_fc  <<<B*64,        256, 0, stream>>>(x, Wc, bc, ws);
  k1b_l2 <<<1,           128, 0, stream>>>(ws);
  k2_amax<<<B*NN*2,      256, 0, stream>>>(ws);
  k2b_tr <<<B*16*16,     256, 0, stream>>>(ws);
  k3_gemm<<<B*KSPL*32,   256, 0, stream>>>(ws);
  k4_out <<<B*4,         256, 0, stream>>>(Wg, bg, ws, out);
}

// Round 5
// 208.873 us; speedup vs baseline: 1.2984x; 1.2984x over previous
//
#include <hip/hip_runtime.h>
#include <hip/hip_bf16.h>
#include <math.h>

// Problem constants
#define B    8
#define C4   64
#define CQ   16
#define NN   512
#define L4   12
#define NCH1 8            // n's per k1 block
#define KSPL 4            // K-split in pass-2 GEMM
#define KT   128          // k-tile in final kernel

// workspace layout (float offsets)
#define O_T    0                              // T[b][n][c][q] (m=c*16+q)   4194304
#define O_FL   (O_T + (size_t)B*NN*C4*CQ)     // Fl[b][q][k]                  65536
#define O_XX   (O_FL + (size_t)B*CQ*NN)       // [B][CQ]                        128
#define O_YY   (O_XX + B*CQ)                  //                                128
#define O_L2   (O_YY + B*CQ)                  // [B] 1/l2 (+pad)                 16
#define O_AMAX (O_L2 + 16)                    // A[b][n][k]                 2097152
#define O_WARR (O_AMAX + (size_t)B*NN*NN)     // W[b][n][k]=A[b][k][n]      2097152
#define O_PART (O_WARR + (size_t)B*NN*NN)     // [B][KSPL][C4][NN]          1048576

// bank-swizzled LDS indexer for k2 Fl tile: +4-float skew every 32 columns
#define FLS_IDX(q, col)  ((q)*288 + (col) + ((((col)>>5))<<2))   // rows of 256 -> 288

// K1: Fc, Fl, norms, and T[n,c,q] = sum_j Fc[q,n,j]*x[c,n,j]
__global__ __launch_bounds__(256) void k1_fc(const float* __restrict__ x,
                                             const float* __restrict__ Wc,
                                             const float* __restrict__ bc,
                                             float* __restrict__ ws) {
  int blk = blockIdx.x;                // b*64 + nchunk
  int b = blk >> 6;
  int n0 = (blk & 63) * NCH1;
  int t = threadIdx.x;
  __shared__ __align__(16) float xs[C4*NCH1*L4];   // [c][nl][j] 6144
  __shared__ float wcs[CQ*C4];                     // [q][c]
  __shared__ float bcs[CQ];
  __shared__ __align__(16) float fcs[NCH1*CQ*L4];  // [nl][q][j] 1536

  for (int e = t; e < CQ*C4; e += 256) wcs[e] = Wc[e];
  if (t < CQ) bcs[t] = bc[t];
  const float* xb = x + (size_t)b*C4*NN*L4 + (size_t)n0*L4;
  for (int f = t; f < (C4*NCH1*L4)/4; f += 256) {
    int c = f / (NCH1*L4/4);
    int r = f - c*(NCH1*L4/4);
    float4 v = *(const float4*)(xb + (size_t)c*NN*L4 + r*4);
    *(float4*)(xs + c*(NCH1*L4) + r*4) = v;
  }
  __syncthreads();
  for (int e = t; e < NCH1*CQ*L4; e += 256) {
    int nl = e / (CQ*L4);
    int rem = e - nl*(CQ*L4);
    int q = rem / L4, j = rem - q*L4;
    float acc = bcs[q];
    #pragma unroll
    for (int c = 0; c < C4; ++c) acc += wcs[q*C4 + c] * xs[c*(NCH1*L4) + nl*L4 + j];
    fcs[e] = acc;
    if (j == L4-1) ws[O_FL + ((size_t)b*CQ + q)*NN + n0 + nl] = acc;
  }
  __syncthreads();
  if (t < CQ) {
    float yy = 0.f, xx = 0.f;
    for (int nl = 0; nl < NCH1; ++nl) {
      #pragma unroll
      for (int j = 0; j < L4; ++j) { float v = fcs[nl*(CQ*L4) + t*L4 + j]; yy += v*v; }
      float w = fcs[nl*(CQ*L4) + t*L4 + (L4-1)];
      xx += w*w;
    }
    atomicAdd(ws + O_YY + b*CQ + t, yy);
    atomicAdd(ws + O_XX + b*CQ + t, xx);
  }
  {
    int c = t >> 2, q0 = (t & 3) * 4;
    for (int nl = 0; nl < NCH1; ++nl) {
      float xr[L4];
      *(float4*)&xr[0] = *(const float4*)(xs + c*(NCH1*L4) + nl*L4);
      *(float4*)&xr[4] = *(const float4*)(xs + c*(NCH1*L4) + nl*L4 + 4);
      *(float4*)&xr[8] = *(const float4*)(xs + c*(NCH1*L4) + nl*L4 + 8);
      float4 tv; float* tvp = (float*)&tv;
      #pragma unroll
      for (int i = 0; i < 4; ++i) {
        float a = 0.f;
        #pragma unroll
        for (int j = 0; j < L4; ++j) a += fcs[nl*(CQ*L4) + (q0+i)*L4 + j] * xr[j];
        tvp[i] = a;
      }
      *(float4*)(ws + O_T + ((size_t)b*NN + n0 + nl)*(C4*CQ) + t*4) = tv;
    }
  }
}

// K1b: l2inv[b]
__global__ void k1b_l2(float* __restrict__ ws) {
  int t = threadIdx.x;              // 128 threads = B*CQ
  __shared__ float s[B*CQ];
  s[t] = sqrtf(ws[O_XX + t]) * sqrtf(ws[O_YY + t]);
  __syncthreads();
  if (t < B) {
    float sum = 0.f;
    #pragma unroll
    for (int q = 0; q < CQ; ++q) sum += s[t*CQ + q];
    ws[O_L2 + t] = 1.0f / sum;
  }
}

// K2 (pass 1): per (n, khalf): R[c 64][k 256] = Tt^T(16x64) * Fl(16x256),
// A[n][k] = relu(tanh(l2inv * max_c R)). 256 thr = 8 cg x 32 kg, frag 8c x 8k.
__global__ __launch_bounds__(256, 4) void k2_amax(float* __restrict__ ws) {
  int blk = blockIdx.x;             // (b*512+n)*2 + khalf
  int khalf = blk & 1;
  int bn = blk >> 1;
  int b = bn >> 9;
  int t = threadIdx.x;
  int cg = t >> 5;                  // 0..7
  int kg = t & 31;                  // 0..31
  __shared__ __align__(16) float Tt[16*64];     // [q][c]
  __shared__ __align__(16) float Fls[16*288];   // swizzled [q][256]
  __shared__ __align__(16) float red[8*264];    // [cg][256+pad]
  {
    float4 v = *(const float4*)(ws + O_T + (size_t)bn*1024 + t*4);
    int c = t >> 2, q0 = (t & 3) * 4;
    Tt[ q0     *64 + c] = v.x;
    Tt[(q0+1)*64 + c] = v.y;
    Tt[(q0+2)*64 + c] = v.z;
    Tt[(q0+3)*64 + c] = v.w;
  }
  const float* flb = ws + O_FL + (size_t)b*CQ*NN + khalf*256;
  #pragma unroll
  for (int i = 0; i < 4; ++i) {
    int f = t + 256*i;              // 0..1023 float4s
    int q = f >> 6, col = (f & 63) * 4;
    float4 v = *(const float4*)(flb + (size_t)q*NN + col);
    *(float4*)&Fls[FLS_IDX(q, col)] = v;
  }
  float l2inv = ws[O_L2 + b];
  __syncthreads();
  float acc[8][8];
  #pragma unroll
  for (int i = 0; i < 8; ++i)
    #pragma unroll
    for (int j = 0; j < 8; ++j) acc[i][j] = 0.f;
  #pragma unroll
  for (int q = 0; q < 16; ++q) {
    float a[8], bb[8];
    *(float4*)&a[0] = *(const float4*)&Tt[q*64 + cg*8];       // broadcast (2 addrs/wave)
    *(float4*)&a[4] = *(const float4*)&Tt[q*64 + cg*8 + 4];
    *(float4*)&bb[0] = *(const float4*)&Fls[FLS_IDX(q, kg*8)];
    *(float4*)&bb[4] = *(const float4*)&Fls[FLS_IDX(q, kg*8) + 4];
    #pragma unroll
    for (int i = 0; i < 8; ++i)
      #pragma unroll
      for (int j = 0; j < 8; ++j) acc[i][j] += a[i]*bb[j];
  }
  float m[8];
  #pragma unroll
  for (int j = 0; j < 8; ++j) {
    float mm = acc[0][j];
    #pragma unroll
    for (int i = 1; i < 8; ++i) mm = fmaxf(mm, acc[i][j]);
    m[j] = mm;
  }
  *(float4*)&red[cg*264 + kg*8]     = *(float4*)&m[0];
  *(float4*)&red[cg*264 + kg*8 + 4] = *(float4*)&m[4];
  __syncthreads();
  float mm = red[t];
  #pragma unroll
  for (int g = 1; g < 8; ++g) mm = fmaxf(mm, red[g*264 + t]);
  float aout = fmaxf(tanhf(mm*l2inv), 0.f);
  ws[O_AMAX + (size_t)bn*NN + khalf*256 + t] = aout;
}

// K2b: W[b][n][k] = A[b][k][n]
__global__ __launch_bounds__(256) void k2b_tr(float* __restrict__ ws) {
  int blk = blockIdx.x;             // b*256 + bi*16 + bj
  int b  = blk >> 8;
  int bi = (blk >> 4) & 15;
  int bj = blk & 15;
  int t = threadIdx.x;
  int tx = t & 31, ty = t >> 5;
  __shared__ float tile[32][33];
  const float* am = ws + O_AMAX + (size_t)b*NN*NN;
  float* wa = ws + O_WARR + (size_t)b*NN*NN;
  #pragma unroll
  for (int i = 0; i < 4; ++i) {
    int row = ty + i*8;
    tile[row][tx] = am[(size_t)(bi*32+row)*NN + bj*32 + tx];
  }
  __syncthreads();
  #pragma unroll
  for (int i = 0; i < 4; ++i) {
    int row = ty + i*8;
    wa[(size_t)(bj*32+row)*NN + bi*32 + tx] = tile[tx][row];
  }
}

// K3 (pass 2): U[m,k] = sum_n T[n,m]*W[n,k]; epilogue q-reduce with Fl*l2inv.
// Grid: ((b*4+ks)*2+kb)*8+mb = 512 blocks. Block 256 thr = 4 waves.
// m-tile 128 (wave w: m = mb*128 + w*32 + mg*8 + i, mg 0..3; A broadcast),
// k-tile 256 (lane owns k = kb*256 + lane*4 .. +4; contiguous b128, 0-conflict),
// n-range 128 staged in 8 subs of 16. acc = 128 VGPR; (256,2) -> no spill.
__global__ __launch_bounds__(256, 2) void k3_gemm(float* __restrict__ ws) {
  int id = blockIdx.x;
  int mb = id & 7;
  int kb = (id >> 3) & 1;
  int ks = (id >> 4) & 3;
  int b  = id >> 6;
  int t = threadIdx.x;
  int w = t >> 6;                   // wave 0..3
  int lane = t & 63;
  __shared__ __align__(16) float Ts[16*128];   // [nl][m_local]
  __shared__ __align__(16) float Ws_[16*256];  // [nl][k_local]
  float acc[4][8][4];
  #pragma unroll
  for (int g = 0; g < 4; ++g)
    #pragma unroll
    for (int i = 0; i < 8; ++i)
      #pragma unroll
      for (int j = 0; j < 4; ++j) acc[g][i][j] = 0.f;
  const float* Wb = ws + O_WARR + (size_t)b*NN*NN + kb*256;   // [n][k]
  const float* Tb = ws + O_T + (size_t)b*NN*1024 + mb*128;    // [n][m]

  for (int sub = 0; sub < 8; ++sub) {
    int n0 = ks*128 + sub*16;
    __syncthreads();
    #pragma unroll
    for (int i = 0; i < 4; ++i) {   // W: 16 rows x 256 cols
      int f = t + 256*i;
      int nl = f >> 6, col = (f & 63) * 4;
      *(float4*)(Ws_ + nl*256 + col) = *(const float4*)(Wb + (size_t)(n0+nl)*NN + col);
    }
    #pragma unroll
    for (int i = 0; i < 2; ++i) {   // T: 16 rows x 128 cols
      int f = t + 256*i;
      int nl = f >> 5, col = (f & 31) * 4;
      *(float4*)(Ts + nl*128 + col) = *(const float4*)(Tb + (size_t)(n0+nl)*1024 + col);
    }
    __syncthreads();
    for (int nl = 0; nl < 16; ++nl) {
      float wf[4];
      *(float4*)wf = *(const float4*)(Ws_ + nl*256 + lane*4);
      #pragma unroll
      for (int g = 0; g < 4; ++g) {
        float a[8];
        *(float4*)&a[0] = *(const float4*)(Ts + nl*128 + w*32 + g*8);      // broadcast
        *(float4*)&a[4] = *(const float4*)(Ts + nl*128 + w*32 + g*8 + 4);  // broadcast
        #pragma unroll
        for (int i = 0; i < 8; ++i)
          #pragma unroll
          for (int j = 0; j < 4; ++j) acc[g][i][j] += a[i]*wf[j];
      }
    }
  }
  // epilogue: c = mb*8 + w*2 + cc (cc = g>>1), q = (g&1)*8 + i
  float l2inv = ws[O_L2 + b];
  const float* flb = ws + O_FL + (size_t)b*CQ*NN + kb*256;
  #pragma unroll
  for (int cc = 0; cc < 2; ++cc) {
    float s[4] = {0.f, 0.f, 0.f, 0.f};
    #pragma unroll
    for (int qg = 0; qg < 2; ++qg) {
      int g = cc*2 + qg;
      #pragma unroll
      for (int i = 0; i < 8; ++i) {
        int q = qg*8 + i;
        float f[4];
        *(float4*)f = *(const float4*)(flb + (size_t)q*NN + lane*4);
        #pragma unroll
        for (int j = 0; j < 4; ++j) s[j] += f[j]*acc[g][i][j];
      }
    }
    #pragma unroll
    for (int j = 0; j < 4; ++j) s[j] *= l2inv;
    int c = mb*8 + w*2 + cc;
    float* outp = ws + O_PART + (((size_t)(b*KSPL + ks)*C4 + c)*NN) + kb*256;
    *(float4*)(outp + lane*4) = *(float4*)s;
  }
}

// K4: reduce KSPL partials -> xg, then Fg = W_gcn xg + b_gcn
__global__ __launch_bounds__(256) void k4_out(const float* __restrict__ Wg,
                                              const float* __restrict__ bg,
                                              const float* __restrict__ ws,
                                              float* __restrict__ out) {
  int blk = blockIdx.x;             // b*4 + kc
  int b = blk >> 2, kc = blk & 3;
  int t = threadIdx.x;
  __shared__ float xg[C4][KT+1];
  __shared__ float wg[C4*C4];
  for (int e = t; e < C4*C4; e += 256) wg[e] = Wg[e];
  for (int e = t; e < C4*KT; e += 256) {
    int c = e >> 7, kk = e & (KT-1);
    float s = 0.f;
    #pragma unroll
    for (int chn = 0; chn < KSPL; ++chn)
      s += ws[O_PART + (((size_t)(b*KSPL + chn)*C4 + c)*NN) + kc*KT + kk];
    xg[c][kk] = s;
  }
  __syncthreads();
  int kk = t & (KT-1);
  int ohalf = t >> 7;
  for (int oi = 0; oi < 32; ++oi) {
    int o = ohalf*32 + oi;
    float acc = bg[o];
    #pragma unroll
    for (int c = 0; c < C4; ++c) acc += wg[o*C4 + c] * xg[c][kk];
    out[((size_t)(b*C4 + o))*NN + kc*KT + kk] = acc;
  }
}

extern "C" void kernel_launch(void* const* d_in, const int* in_sizes, int n_in,
                              void* d_out, int out_size, void* d_ws, size_t ws_size,
                              hipStream_t stream) {
  const float* x  = (const float*)d_in[0];
  const float* Wc = (const float*)d_in[1];
  const float* bc = (const float*)d_in[2];
  const float* Wg = (const float*)d_in[3];
  const float* bg = (const float*)d_in[4];
  float* ws  = (float*)d_ws;
  float* out = (float*)d_out;

  hipMemsetAsync(ws + O_XX, 0, (2*B*CQ + 16)*sizeof(float), stream);

  k1_fc  <<<B*64,        256, 0, stream>>>(x, Wc, bc, ws);
  k1b_l2 <<<1,           128, 0, stream>>>(ws);
  k2_amax<<<B*NN*2,      256, 0, stream>>>(ws);
  k2b_tr <<<B*16*16,     256, 0, stream>>>(ws);
  k3_gemm<<<B*KSPL*2*8,  256, 0, stream>>>(ws);
  k4_out <<<B*4,         256, 0, stream>>>(Wg, bg, ws, out);
}

// Round 6
// 206.338 us; speedup vs baseline: 1.3144x; 1.0123x over previous
//
#include <hip/hip_runtime.h>
#include <hip/hip_bf16.h>
#include <math.h>

// Problem constants
#define B    8
#define C4   64
#define CQ   16
#define NN   512
#define L4   12
#define NCH1 8            // n's per k1 block
#define KSPL 4            // K-split in pass-2 GEMM
#define KT   128          // k-tile in final kernel

// workspace layout (float offsets)
#define O_T    0                              // T[b][n][c][q] (m=c*16+q)   4194304
#define O_FL   (O_T + (size_t)B*NN*C4*CQ)     // Fl[b][q][k]                  65536
#define O_XX   (O_FL + (size_t)B*CQ*NN)       // [B][CQ]                        128
#define O_YY   (O_XX + B*CQ)                  //                                128
#define O_L2   (O_YY + B*CQ)                  // [B] 1/l2 (+pad)                 16
#define O_AMAX (O_L2 + 16)                    // A[b][n][k]                 2097152
#define O_WARR (O_AMAX + (size_t)B*NN*NN)     // W[b][n][k]=A[b][k][n]      2097152
#define O_PART (O_WARR + (size_t)B*NN*NN)     // [B][KSPL][C4][NN]          1048576

// K1: Fc, Fl, norms, and T[n,c,q] = sum_j Fc[q,n,j]*x[c,n,j]
__global__ __launch_bounds__(256) void k1_fc(const float* __restrict__ x,
                                             const float* __restrict__ Wc,
                                             const float* __restrict__ bc,
                                             float* __restrict__ ws) {
  int blk = blockIdx.x;                // b*64 + nchunk
  int b = blk >> 6;
  int n0 = (blk & 63) * NCH1;
  int t = threadIdx.x;
  __shared__ __align__(16) float xs[C4*NCH1*L4];   // [c][nl][j] 6144
  __shared__ float wcs[CQ*C4];                     // [q][c]
  __shared__ float bcs[CQ];
  __shared__ __align__(16) float fcs[NCH1*CQ*L4];  // [nl][q][j] 1536

  for (int e = t; e < CQ*C4; e += 256) wcs[e] = Wc[e];
  if (t < CQ) bcs[t] = bc[t];
  const float* xb = x + (size_t)b*C4*NN*L4 + (size_t)n0*L4;
  for (int f = t; f < (C4*NCH1*L4)/4; f += 256) {
    int c = f / (NCH1*L4/4);
    int r = f - c*(NCH1*L4/4);
    float4 v = *(const float4*)(xb + (size_t)c*NN*L4 + r*4);
    *(float4*)(xs + c*(NCH1*L4) + r*4) = v;
  }
  __syncthreads();
  for (int e = t; e < NCH1*CQ*L4; e += 256) {
    int nl = e / (CQ*L4);
    int rem = e - nl*(CQ*L4);
    int q = rem / L4, j = rem - q*L4;
    float acc = bcs[q];
    #pragma unroll
    for (int c = 0; c < C4; ++c) acc += wcs[q*C4 + c] * xs[c*(NCH1*L4) + nl*L4 + j];
    fcs[e] = acc;
    if (j == L4-1) ws[O_FL + ((size_t)b*CQ + q)*NN + n0 + nl] = acc;
  }
  __syncthreads();
  if (t < CQ) {
    float yy = 0.f, xx = 0.f;
    for (int nl = 0; nl < NCH1; ++nl) {
      #pragma unroll
      for (int j = 0; j < L4; ++j) { float v = fcs[nl*(CQ*L4) + t*L4 + j]; yy += v*v; }
      float w = fcs[nl*(CQ*L4) + t*L4 + (L4-1)];
      xx += w*w;
    }
    atomicAdd(ws + O_YY + b*CQ + t, yy);
    atomicAdd(ws + O_XX + b*CQ + t, xx);
  }
  {
    int c = t >> 2, q0 = (t & 3) * 4;
    for (int nl = 0; nl < NCH1; ++nl) {
      float xr[L4];
      *(float4*)&xr[0] = *(const float4*)(xs + c*(NCH1*L4) + nl*L4);
      *(float4*)&xr[4] = *(const float4*)(xs + c*(NCH1*L4) + nl*L4 + 4);
      *(float4*)&xr[8] = *(const float4*)(xs + c*(NCH1*L4) + nl*L4 + 8);
      float4 tv; float* tvp = (float*)&tv;
      #pragma unroll
      for (int i = 0; i < 4; ++i) {
        float a = 0.f;
        #pragma unroll
        for (int j = 0; j < L4; ++j) a += fcs[nl*(CQ*L4) + (q0+i)*L4 + j] * xr[j];
        tvp[i] = a;
      }
      *(float4*)(ws + O_T + ((size_t)b*NN + n0 + nl)*(C4*CQ) + t*4) = tv;
    }
  }
}

// K1b: l2inv[b]
__global__ void k1b_l2(float* __restrict__ ws) {
  int t = threadIdx.x;              // 128 threads = B*CQ
  __shared__ float s[B*CQ];
  s[t] = sqrtf(ws[O_XX + t]) * sqrtf(ws[O_YY + t]);
  __syncthreads();
  if (t < B) {
    float sum = 0.f;
    #pragma unroll
    for (int q = 0; q < CQ; ++q) sum += s[t*CQ + q];
    ws[O_L2 + t] = 1.0f / sum;
  }
}

// K2 (pass 1): one block per (b,n). R[c][k] = sum_q Tt[q][c]*Fl[q][k].
// Wave w owns c-range w*16 (broadcast Tt); lane owns k = lane*4 (+256 half).
// acc[16][8] = 128 VGPR. Intra-wave max over c, LDS max across 4 waves.
__global__ __launch_bounds__(256, 2) void k2_amax(float* __restrict__ ws) {
  int bn = blockIdx.x;              // b*512 + n
  int b = bn >> 9;
  int t = threadIdx.x;
  int w = t >> 6;
  int lane = t & 63;
  __shared__ __align__(16) float Tt[16*64];     // [q][c]
  __shared__ __align__(16) float Fls[16*512];   // [q][k]
  __shared__ __align__(16) float red[3*512];
  {
    float4 v = *(const float4*)(ws + O_T + (size_t)bn*1024 + t*4);
    int c = t >> 2, q0 = (t & 3) * 4;
    Tt[ q0   *64 + c] = v.x;
    Tt[(q0+1)*64 + c] = v.y;
    Tt[(q0+2)*64 + c] = v.z;
    Tt[(q0+3)*64 + c] = v.w;
  }
  const float* flb = ws + O_FL + (size_t)b*CQ*NN;
  #pragma unroll
  for (int i = 0; i < 8; ++i) {
    int f = t + 256*i;              // 2048 float4s: [q][512]
    int q = f >> 7, col = (f & 127) * 4;
    *(float4*)(Fls + q*512 + col) = *(const float4*)(flb + (size_t)q*NN + col);
  }
  float l2inv = ws[O_L2 + b];
  __syncthreads();
  float acc[16][8];
  #pragma unroll
  for (int i = 0; i < 16; ++i)
    #pragma unroll
    for (int j = 0; j < 8; ++j) acc[i][j] = 0.f;
  #pragma unroll
  for (int q = 0; q < 16; ++q) {
    float a[16], b0[4], b1[4];
    #pragma unroll
    for (int g = 0; g < 4; ++g)
      *(float4*)&a[g*4] = *(const float4*)&Tt[q*64 + w*16 + g*4];   // broadcast
    *(float4*)b0 = *(const float4*)&Fls[q*512 + lane*4];
    *(float4*)b1 = *(const float4*)&Fls[q*512 + 256 + lane*4];
    #pragma unroll
    for (int i = 0; i < 16; ++i) {
      #pragma unroll
      for (int j = 0; j < 4; ++j) {
        acc[i][j]   += a[i]*b0[j];
        acc[i][4+j] += a[i]*b1[j];
      }
    }
  }
  // intra-wave max over 16 c's
  float m[8];
  #pragma unroll
  for (int j = 0; j < 8; ++j) {
    float mm = acc[0][j];
    #pragma unroll
    for (int i = 1; i < 16; ++i) mm = fmaxf(mm, acc[i][j]);
    m[j] = mm;
  }
  if (w > 0) {
    *(float4*)&red[(w-1)*512 + lane*4]       = *(float4*)&m[0];
    *(float4*)&red[(w-1)*512 + 256 + lane*4] = *(float4*)&m[4];
  }
  __syncthreads();
  if (w == 0) {
    #pragma unroll
    for (int g = 0; g < 3; ++g) {
      float4 p0 = *(const float4*)&red[g*512 + lane*4];
      float4 p1 = *(const float4*)&red[g*512 + 256 + lane*4];
      m[0] = fmaxf(m[0], p0.x); m[1] = fmaxf(m[1], p0.y);
      m[2] = fmaxf(m[2], p0.z); m[3] = fmaxf(m[3], p0.w);
      m[4] = fmaxf(m[4], p1.x); m[5] = fmaxf(m[5], p1.y);
      m[6] = fmaxf(m[6], p1.z); m[7] = fmaxf(m[7], p1.w);
    }
    float o[8];
    #pragma unroll
    for (int j = 0; j < 8; ++j) o[j] = fmaxf(tanhf(m[j]*l2inv), 0.f);
    float* am = ws + O_AMAX + (size_t)bn*NN;
    *(float4*)(am + lane*4)       = *(float4*)&o[0];
    *(float4*)(am + 256 + lane*4) = *(float4*)&o[4];
  }
}

// K2b: W[b][n][k] = A[b][k][n]
__global__ __launch_bounds__(256) void k2b_tr(float* __restrict__ ws) {
  int blk = blockIdx.x;             // b*256 + bi*16 + bj
  int b  = blk >> 8;
  int bi = (blk >> 4) & 15;
  int bj = blk & 15;
  int t = threadIdx.x;
  int tx = t & 31, ty = t >> 5;
  __shared__ float tile[32][33];
  const float* am = ws + O_AMAX + (size_t)b*NN*NN;
  float* wa = ws + O_WARR + (size_t)b*NN*NN;
  #pragma unroll
  for (int i = 0; i < 4; ++i) {
    int row = ty + i*8;
    tile[row][tx] = am[(size_t)(bi*32+row)*NN + bj*32 + tx];
  }
  __syncthreads();
  #pragma unroll
  for (int i = 0; i < 4; ++i) {
    int row = ty + i*8;
    wa[(size_t)(bj*32+row)*NN + bi*32 + tx] = tile[tx][row];
  }
}

// K3 (pass 2): U[m,k] = sum_n T[n,m]*W[n,k]; epilogue q-reduce with Fl*l2inv.
// Grid: (b*4+ks)*16+mb = 512 blocks. Block 256 thr = 4 waves.
// m-tile 64: wave w owns m = mb*64 + w*16 + q  ->  exactly c = mb*4+w, all q.
// k-tile 512: lane owns k = lane*4 and 256+lane*4. acc[16][8] = 128 VGPR.
__global__ __launch_bounds__(256, 2) void k3_gemm(float* __restrict__ ws) {
  int id = blockIdx.x;
  int mb = id & 15;
  int ks = (id >> 4) & 3;
  int b  = id >> 6;
  int t = threadIdx.x;
  int w = t >> 6;                   // wave 0..3
  int lane = t & 63;
  __shared__ __align__(16) float Ts[16*64];    // [nl][m_local]
  __shared__ __align__(16) float Ws_[16*512];  // [nl][k]
  float acc[16][8];
  #pragma unroll
  for (int i = 0; i < 16; ++i)
    #pragma unroll
    for (int j = 0; j < 8; ++j) acc[i][j] = 0.f;
  const float* Wb = ws + O_WARR + (size_t)b*NN*NN;            // [n][k]
  const float* Tb = ws + O_T + (size_t)b*NN*1024 + mb*64;     // [n][m]

  for (int sub = 0; sub < 8; ++sub) {
    int n0 = ks*128 + sub*16;
    __syncthreads();
    #pragma unroll
    for (int i = 0; i < 8; ++i) {   // W: 16 rows x 512 cols
      int f = t + 256*i;
      int nl = f >> 7, col = (f & 127) * 4;
      *(float4*)(Ws_ + nl*512 + col) = *(const float4*)(Wb + (size_t)(n0+nl)*NN + col);
    }
    {                               // T: 16 rows x 64 cols
      int nl = t >> 4, col = (t & 15) * 4;
      *(float4*)(Ts + nl*64 + col) = *(const float4*)(Tb + (size_t)(n0+nl)*1024 + col);
    }
    __syncthreads();
    for (int nl = 0; nl < 16; ++nl) {
      float a[16], wf0[4], wf1[4];
      #pragma unroll
      for (int g = 0; g < 4; ++g)
        *(float4*)&a[g*4] = *(const float4*)(Ts + nl*64 + w*16 + g*4);   // broadcast
      *(float4*)wf0 = *(const float4*)(Ws_ + nl*512 + lane*4);
      *(float4*)wf1 = *(const float4*)(Ws_ + nl*512 + 256 + lane*4);
      #pragma unroll
      for (int i = 0; i < 16; ++i) {
        #pragma unroll
        for (int j = 0; j < 4; ++j) {
          acc[i][j]   += a[i]*wf0[j];
          acc[i][4+j] += a[i]*wf1[j];
        }
      }
    }
  }
  // epilogue: c = mb*4 + w; q = i. s[k] = sum_q Fl[q][k]*acc[q][k] * l2inv
  float l2inv = ws[O_L2 + b];
  const float* flb = ws + O_FL + (size_t)b*CQ*NN;
  float s[8];
  #pragma unroll
  for (int j = 0; j < 8; ++j) s[j] = 0.f;
  #pragma unroll
  for (int i = 0; i < 16; ++i) {
    float f0[4], f1[4];
    *(float4*)f0 = *(const float4*)(flb + (size_t)i*NN + lane*4);
    *(float4*)f1 = *(const float4*)(flb + (size_t)i*NN + 256 + lane*4);
    #pragma unroll
    for (int j = 0; j < 4; ++j) {
      s[j]   += f0[j]*acc[i][j];
      s[4+j] += f1[j]*acc[i][4+j];
    }
  }
  #pragma unroll
  for (int j = 0; j < 8; ++j) s[j] *= l2inv;
  int c = mb*4 + w;
  float* outp = ws + O_PART + (((size_t)(b*KSPL + ks)*C4 + c)*NN);
  *(float4*)(outp + lane*4)       = *(float4*)&s[0];
  *(float4*)(outp + 256 + lane*4) = *(float4*)&s[4];
}

// K4: reduce KSPL partials -> xg, then Fg = W_gcn xg + b_gcn
__global__ __launch_bounds__(256) void k4_out(const float* __restrict__ Wg,
                                              const float* __restrict__ bg,
                                              const float* __restrict__ ws,
                                              float* __restrict__ out) {
  int blk = blockIdx.x;             // b*4 + kc
  int b = blk >> 2, kc = blk & 3;
  int t = threadIdx.x;
  __shared__ float xg[C4][KT+1];
  __shared__ float wg[C4*C4];
  for (int e = t; e < C4*C4; e += 256) wg[e] = Wg[e];
  for (int e = t; e < C4*KT; e += 256) {
    int c = e >> 7, kk = e & (KT-1);
    float s = 0.f;
    #pragma unroll
    for (int chn = 0; chn < KSPL; ++chn)
      s += ws[O_PART + (((size_t)(b*KSPL + chn)*C4 + c)*NN) + kc*KT + kk];
    xg[c][kk] = s;
  }
  __syncthreads();
  int kk = t & (KT-1);
  int ohalf = t >> 7;
  for (int oi = 0; oi < 32; ++oi) {
    int o = ohalf*32 + oi;
    float acc = bg[o];
    #pragma unroll
    for (int c = 0; c < C4; ++c) acc += wg[o*C4 + c] * xg[c][kk];
    out[((size_t)(b*C4 + o))*NN + kc*KT + kk] = acc;
  }
}

extern "C" void kernel_launch(void* const* d_in, const int* in_sizes, int n_in,
                              void* d_out, int out_size, void* d_ws, size_t ws_size,
                              hipStream_t stream) {
  const float* x  = (const float*)d_in[0];
  const float* Wc = (const float*)d_in[1];
  const float* bc = (const float*)d_in[2];
  const float* Wg = (const float*)d_in[3];
  const float* bg = (const float*)d_in[4];
  float* ws  = (float*)d_ws;
  float* out = (float*)d_out;

  hipMemsetAsync(ws + O_XX, 0, (2*B*CQ + 16)*sizeof(float), stream);

  k1_fc  <<<B*64,        256, 0, stream>>>(x, Wc, bc, ws);
  k1b_l2 <<<1,           128, 0, stream>>>(ws);
  k2_amax<<<B*NN,        256, 0, stream>>>(ws);
  k2b_tr <<<B*16*16,     256, 0, stream>>>(ws);
  k3_gemm<<<B*KSPL*16,   256, 0, stream>>>(ws);
  k4_out <<<B*4,         256, 0, stream>>>(Wg, bg, ws, out);
}